// Round 11
// baseline (52.566 us; speedup 1.0000x reference)
//
#include <hip/hip_runtime.h>
#include <hip/hip_cooperative_groups.h>

namespace cg = cooperative_groups;

// (B,C,H,W) = (8,19,512,512), fp32 everywhere.
constexpr int B_ = 8, C_ = 19, H_ = 512, W_ = 512;
constexpr int HW_ = H_ * W_;
constexpr int NB = 512;    // blocks (2/CU on 256 CUs)
constexpr int NT = 1024;   // threads (16 waves) -> 2048 threads/CU = 100% occ

// LDS (floats): [0..14336) work region; [14336..14848) A-table; [14848..14880) saw
constexpr int LDSF    = 14880;  // 59520 B -> 2 blocks/CU
constexpr int A_OFF   = 14336;
constexpr int SAW_OFF = 14848;
// eye-phase layout: xh 36x292 at 0; tile2 10x292 at 10512; wh 10x260 at 0 (over dead xh)
constexpr int XH_S = 292, T2_OFF = 10512, T2_S = 292, WH_S = 260;
// phase-B layout: st 8x540 at 0
constexpr int ST_S = 540;

__device__ __forceinline__ int refl(int i, int n) {
    i = (i < 0) ? -i : i;
    return (i >= n) ? (2 * n - 2 - i) : i;
}

// Distance-indexed normalized Gaussian weights in registers.
template<int ND>
__device__ __forceinline__ void gauss_reg(float (&wkr)[ND], float sigma) {
    float s = 0.f;
#pragma unroll
    for (int d = 0; d < ND; ++d) {
        const float t = d / sigma;
        wkr[d] = expf(-0.5f * t * t);
        s += (d ? 2.f : 1.f) * wkr[d];
    }
    const float inv = 1.f / s;
#pragma unroll
    for (int d = 0; d < ND; ++d) wkr[d] *= inv;
}

// Total-contribution weight of input position i under the K=21 reflect blur.
__device__ __forceinline__ float aweight(int i, const float (&wkr)[11]) {
    float a = 0.f;
#pragma unroll
    for (int t = 0; t < 21; ++t) {
        const float k = wkr[(t < 10) ? (10 - t) : (t - 10)];
        const int o = i + 10 - t;
        if (o >= 0 && o < H_) a += k;
        if (i >= 1 && i <= 10 && t <= 10 - i) a += k;
        if (i >= 501 && i <= 510 && t >= 521 - i) a += k;
    }
    return a;
}

// workspace (floats):
//   [0..512)      blockmax (z*32 + ht), z = eye*8 + b
//   [512..1024)   eyesumw  (z*32 + ht)
//   [1024..1536)  esum     (vb = b*64 + chunk)
//   [16384..)     t0: 24 images (0..7 w_l, 8..15 w_r, 16..23 einsum out)
// vb decode everywhere: b = vb>>6 (all of batch b lives on XCD b).

// ========== Phase A part 1: HALF-RES eye pipeline (16 full rows/block) =====
__device__ __forceinline__ void eye_tile(const float* __restrict__ mp,
                                         float* __restrict__ t0,
                                         float* __restrict__ blockmax,
                                         float* __restrict__ eyesumw,
                                         float* lds, int tid, int vb)
{
    float kh[14];
    gauss_reg(kh, 7.5f);                      // half-res sigma = 15/2
    const int b = vb >> 6, eye = (vb >> 5) & 1, ht = vb & 31;
    const int z = eye * 8 + b;
    const int i0 = ht * 8;                    // first half-row of this tile
    const float* sb = mp + ((long)b * C_ + 4 + eye) * HW_;

    __syncthreads();                          // work region free of prior use
    // ---- S1: box2 downsample into xh[36][292] (slot s = half-row i0-14+s)
    for (int t = 0; t < 5; ++t) {
        const int e = tid + t * NT;
        if (e < 36 * 142) {
            const int s = e / 142, p = e - s * 142;
            const int R = i0 - 14 + s;
            const long r0 = (long)refl(2 * R, H_) * W_;
            const long r1 = (long)refl(2 * R + 1, H_) * W_;
            const int fc = 4 * p - 28;
            float a0, a1;
            if (fc >= 0 && fc + 3 < W_) {
                const float4 u = *(const float4*)(sb + r0 + fc);
                const float4 v = *(const float4*)(sb + r1 + fc);
                a0 = (u.x + u.y + v.x + v.y) * 0.25f;
                a1 = (u.z + u.w + v.z + v.w) * 0.25f;
            } else {
                const int j0 = 2 * p - 14, j1 = j0 + 1;
                a0 = (sb[r0 + refl(2 * j0, W_)] + sb[r0 + refl(2 * j0 + 1, W_)]
                    + sb[r1 + refl(2 * j0, W_)] + sb[r1 + refl(2 * j0 + 1, W_)]) * 0.25f;
                a1 = (sb[r0 + refl(2 * j1, W_)] + sb[r0 + refl(2 * j1 + 1, W_)]
                    + sb[r1 + refl(2 * j1, W_)] + sb[r1 + refl(2 * j1 + 1, W_)]) * 0.25f;
            }
            *(float2*)(lds + s * XH_S + 2 * p) = make_float2(a0, a1);
        }
    }
    __syncthreads();
    // ---- S2: H-blur, register window, split 10 rows into 2 half-windows
    {
        const int half = tid >> 9, cc = tid & 511;
        if (cc < 282) {
            float w2[31];
#pragma unroll
            for (int s = 0; s < 31; ++s) w2[s] = lds[(half * 5 + s) * XH_S + cc + 1];
#pragma unroll
            for (int r = 0; r < 5; ++r) {
                float a = 0.f;
#pragma unroll
                for (int dd = 0; dd < 27; ++dd)
                    a = fmaf(w2[r + dd], kh[(dd < 13) ? (13 - dd) : (dd - 13)], a);
                lds[T2_OFF + (half * 5 + r) * T2_S + cc] = a;
            }
        }
    }
    __syncthreads();
    // ---- S3: W-blur, lane-linear b128 windows -> wh[10][260] (single pass)
    {
        const int r = tid >> 6, g = tid & 63;
        if (r < 10) {
            const float* trow = lds + T2_OFF + r * T2_S + 4 * g;
            float wn[32];
#pragma unroll
            for (int m = 0; m < 8; ++m) {
                const float4 v = *(const float4*)(trow + 4 * m);
                wn[4*m] = v.x; wn[4*m+1] = v.y; wn[4*m+2] = v.z; wn[4*m+3] = v.w;
            }
            float o4[4];
#pragma unroll
            for (int o = 0; o < 4; ++o) {
                float a = 0.f;
#pragma unroll
                for (int dd = 0; dd < 27; ++dd)
                    a = fmaf(wn[o + dd], kh[(dd < 13) ? (13 - dd) : (dd - 13)], a);
                o4[o] = a;
            }
            *(float4*)(lds + r * WH_S + 4 * g) = make_float4(o4[0], o4[1], o4[2], o4[3]);
        }
    }
    __syncthreads();
    // ---- S4: upsample + mask + write + max / A-weighted sum (rows split 2x)
    const float* A = lds + A_OFF;
    const int c = tid & 511, half = tid >> 9;
    const int j = c >> 1;
    const int jn = (c & 1) ? ((j < 255) ? j + 1 : 255) : ((j > 0) ? j - 1 : 0);
    float cv[6];
#pragma unroll
    for (int s = 0; s < 6; ++s)
        cv[s] = 0.75f * lds[(half * 4 + s) * WH_S + j]
              + 0.25f * lds[(half * 4 + s) * WH_S + jn];
    const float Aw = A[c];
    const long mbase = (long)b * C_ * HW_ + (long)(ht * 16) * W_ + c;
    const float* eyp = mp + mbase + (long)(4 + eye) * HW_;
    const float* bgp = mp + mbase;
    float* db = t0 + (long)z * HW_ + (long)(ht * 16) * W_ + c;
    float vmax = 0.f, vsum = 0.f;
#pragma unroll
    for (int o = 0; o < 8; ++o) {
        const int og = half * 8 + o;           // global row in tile (0..15)
        const int li = (o >> 1) + 1;           // local cv index (1..4)
        const int i  = i0 + half * 4 + (o >> 1);  // global half-row
        const float cvn = (og & 1) ? ((i < 255) ? cv[li + 1] : cv[li])
                                   : ((i > 0)   ? cv[li - 1] : cv[li]);
        const float wv = 0.75f * cv[li] + 0.25f * cvn;
        const float ey = eyp[(long)og * W_], bg = bgp[(long)og * W_];
        const float v = wv * (1.f - ey) * (1.f - bg);
        db[(long)og * W_] = v;
        vmax = fmaxf(vmax, v);
        vsum = fmaf(v, A[ht * 16 + og] * Aw, vsum);
    }
#pragma unroll
    for (int off = 32; off; off >>= 1) {
        vmax = fmaxf(vmax, __shfl_down(vmax, off));
        vsum += __shfl_down(vsum, off);
    }
    __syncthreads();                           // all S4 LDS reads done
    if ((tid & 63) == 0) { lds[tid >> 6] = vmax; lds[16 + (tid >> 6)] = vsum; }
    __syncthreads();
    if (tid == 0) {
        float m = lds[0], s = lds[16];
        for (int i = 1; i < 16; ++i) { m = fmaxf(m, lds[i]); s += lds[16 + i]; }
        blockmax[z * 32 + ht] = m;
        eyesumw[z * 32 + ht] = s;
    }
}

// ========== Phase A part 2: einsum chunk + A-weighted sum ==================
__device__ __forceinline__ void einsum_part(const float* __restrict__ mp,
                                            float* __restrict__ t3,
                                            float* __restrict__ esum,
                                            float* lds, int tid, int vb)
{
    const float* A   = lds + A_OFF;
    const float* saw = lds + SAW_OFF;
    const int b = vb >> 6, chunk = vb & 63;
    const int p4 = chunk * 1024 + tid;            // float4 index in batch
    const long p = (long)p4 * 4;
    const int h = (int)(p >> 9), w0 = (int)(p & 511);
    const float* mpb = mp + (long)b * C_ * HW_ + p;
    float4 acc = make_float4(0.f, 0.f, 0.f, 0.f);
#pragma unroll
    for (int c = 0; c < C_; ++c) {
        const float4 v = *(const float4*)(mpb + (long)c * HW_);
        const float a = saw[c];
        acc.x = fmaf(v.x, a, acc.x);
        acc.y = fmaf(v.y, a, acc.y);
        acc.z = fmaf(v.z, a, acc.z);
        acc.w = fmaf(v.w, a, acc.w);
    }
    *(float4*)(t3 + (long)b * HW_ + p) = acc;
    const float4 a4 = *(const float4*)(A + w0);   // aligned, lane-linear
    float se = (acc.x * a4.x + acc.y * a4.y + acc.z * a4.z + acc.w * a4.w) * A[h];
#pragma unroll
    for (int off = 32; off; off >>= 1) se += __shfl_down(se, off);
    __syncthreads();
    if ((tid & 63) == 0) lds[tid >> 6] = se;
    __syncthreads();
    if (tid == 0) {
        float s = 0.f;
        for (int i = 0; i < 16; ++i) s += lds[i];
        esum[vb] = s;
    }
}

// ========== Phase B: combine + 21-tap blur, register windows ===============
__device__ __forceinline__ void phaseB(const float* __restrict__ esw,
                                       const float* __restrict__ t0,
                                       const float* __restrict__ blockmax,
                                       const float* __restrict__ eyesumw,
                                       const float* __restrict__ esum,
                                       float* __restrict__ out,
                                       float* lds, int tid, int vb)
{
    float wkr[11];
    gauss_reg(wkr, 2.f);
    const int b = vb >> 6, tile6 = vb & 63, hb = tile6 * 8;

    // uniform scalar reductions (identical in every thread)
    float mxL = blockmax[b * 32], mxR = blockmax[(8 + b) * 32];
    float SeL = 0.f, SeR = 0.f, Se = 0.f;
    for (int i = 0; i < 32; ++i) {
        mxL = fmaxf(mxL, blockmax[b * 32 + i]);
        mxR = fmaxf(mxR, blockmax[(8 + b) * 32 + i]);
        SeL += eyesumw[b * 32 + i];
        SeR += eyesumw[(8 + b) * 32 + i];
    }
    for (int i = 0; i < 64; ++i) Se += esum[b * 64 + i];
    const float e = esw[0];
    const float sl = e / mxL, sr = e / mxR;
    const float scale = (float)HW_ / (Se + sl * SeL + sr * SeR);

    const float* t1 = t0 + (long)b * HW_;
    const float* t2 = t0 + (long)(8 + b) * HW_;
    const float* t3 = t0 + (long)(16 + b) * HW_;

    // H-pass: thread = (col, half); combine + 24-row window from global
    const int c = tid & 511, half = tid >> 9;
    float win[24];
#pragma unroll
    for (int i = 0; i < 24; ++i) {
        const long off = (long)refl(hb - 10 + half * 4 + i, H_) * W_ + c;
        win[i] = fmaf(t1[off], sl, fmaf(t2[off], sr, t3[off]));
    }
    float hv[4];
#pragma unroll
    for (int j = 0; j < 4; ++j) {
        float a = 0.f;
#pragma unroll
        for (int k = 0; k < 21; ++k)
            a = fmaf(win[j + k], wkr[(k < 10) ? (10 - k) : (k - 10)], a);
        hv[j] = a;
    }
    float* st = lds;                                   // 8 x 540, col x at 12+x
#pragma unroll
    for (int j = 0; j < 4; ++j) st[(half * 4 + j) * ST_S + 12 + c] = hv[j];
    __syncthreads();
    if (tid < 224) {                                   // 8 rows x 28 halo cols
        const int r = tid / 28, q = tid - r * 28;
        float* srow = st + r * ST_S;
        if (q < 12) srow[11 - q] = srow[13 + q];               // col -(q+1) <- q+1
        else { const int cc = q - 12; srow[524 + cc] = srow[522 - cc]; } // 512+cc <- 510-cc
    }
    __syncthreads();
    // W-pass: 128 threads/row, lane = 4-col group (conflict-free b128 stride)
    const int r = tid >> 7, g = tid & 127, c0 = g * 4;
    const float* srow = st + r * ST_S;                 // col x at srow[12+x]
    float wn[28];                                      // cols c0-12 .. c0+15
#pragma unroll
    for (int m = 0; m < 7; ++m) {
        const float4 v = *(const float4*)(srow + c0 + 4 * m);
        wn[4*m] = v.x; wn[4*m+1] = v.y; wn[4*m+2] = v.z; wn[4*m+3] = v.w;
    }
    float oo[4];
#pragma unroll
    for (int o = 0; o < 4; ++o) {                      // out col c0+o: wn[o+2..o+22]
        float a = 0.f;
#pragma unroll
        for (int k = 0; k < 21; ++k)
            a = fmaf(wn[o + 2 + k], wkr[(k < 10) ? (10 - k) : (k - 10)], a);
        oo[o] = a * scale;
    }
    *(float4*)(out + (long)b * HW_ + (long)(hb + r) * W_ + c0)
        = make_float4(oo[0], oo[1], oo[2], oo[3]);
}

// ===================== cooperative mega kernel (1 grid.sync) ================
__global__ void __launch_bounds__(NT, 8)
mega_kern(const float* __restrict__ mp, const float* __restrict__ aw,
          const float* __restrict__ esw, float* __restrict__ out,
          float* __restrict__ ws)
{
    cg::grid_group grid = cg::this_grid();
    __shared__ __align__(16) float lds[LDSF];
    const int tid = threadIdx.x, bid = blockIdx.x;
    // XCD swizzle with vb>>6 = batch: all of batch b's work lands on XCD b.
    const int vb = (bid & 7) * 64 + (bid >> 3);
    float* blockmax = ws;
    float* eyesumw  = ws + 512;
    float* esum     = ws + 1024;
    float* t0       = ws + 16384;
    float* t3       = t0 + 16L * HW_;

    if (tid < 512) {   // A-weight table (above the work region)
        float w21[11];
        gauss_reg(w21, 2.f);
        lds[A_OFF + tid] = aweight(tid, w21);
    }
    if (tid < C_) lds[SAW_OFF + tid] = aw[tid];
    __syncthreads();

    // parity-alternated order: mixes compute-heavy and BW-heavy work chip-wide
    if (bid & 1) {
        einsum_part(mp, t3, esum, lds, tid, vb);
        eye_tile(mp, t0, blockmax, eyesumw, lds, tid, vb);
    } else {
        eye_tile(mp, t0, blockmax, eyesumw, lds, tid, vb);
        einsum_part(mp, t3, esum, lds, tid, vb);
    }
    grid.sync();
    phaseB(esw, t0, blockmax, eyesumw, esum, out, lds, tid, vb);
}

// ===================== fallback pipeline (2 kernels) =====================
__global__ void __launch_bounds__(NT)
fb_A_kern(const float* __restrict__ mp, const float* __restrict__ aw,
          float* __restrict__ ws)
{
    __shared__ __align__(16) float lds[LDSF];
    const int tid = threadIdx.x, bid = blockIdx.x;
    const int vb = (bid & 7) * 64 + (bid >> 3);
    float* blockmax = ws;
    float* eyesumw  = ws + 512;
    float* esum     = ws + 1024;
    float* t0       = ws + 16384;
    float* t3       = t0 + 16L * HW_;
    if (tid < 512) {
        float w21[11];
        gauss_reg(w21, 2.f);
        lds[A_OFF + tid] = aweight(tid, w21);
    }
    if (tid < C_) lds[SAW_OFF + tid] = aw[tid];
    __syncthreads();
    if (bid & 1) {
        einsum_part(mp, t3, esum, lds, tid, vb);
        eye_tile(mp, t0, blockmax, eyesumw, lds, tid, vb);
    } else {
        eye_tile(mp, t0, blockmax, eyesumw, lds, tid, vb);
        einsum_part(mp, t3, esum, lds, tid, vb);
    }
}

__global__ void __launch_bounds__(NT)
fb_B_kern(const float* __restrict__ esw, float* __restrict__ out,
          float* __restrict__ ws)
{
    __shared__ __align__(16) float lds[LDSF];
    const int tid = threadIdx.x, bid = blockIdx.x;
    const int vb = (bid & 7) * 64 + (bid >> 3);
    phaseB(esw, ws + 16384, ws, ws + 512, ws + 1024, out, lds, tid, vb);
}

extern "C" void kernel_launch(void* const* d_in, const int* in_sizes, int n_in,
                              void* d_out, int out_size, void* d_ws, size_t ws_size,
                              hipStream_t stream)
{
    const float* mp  = (const float*)d_in[0];  // (8,19,512,512) f32
    const float* aw  = (const float*)d_in[1];  // (19,) f32
    const float* esw = (const float*)d_in[2];  // (1,) f32
    float* out = (float*)d_out;                // (8,1,512,512) f32
    float* wsf = (float*)d_ws;

    // Deterministic host-side decision (capture-safe: host queries only).
    int coop = 0, nb = 0;
    hipDeviceGetAttribute(&coop, hipDeviceAttributeCooperativeLaunch, 0);
    hipOccupancyMaxActiveBlocksPerMultiprocessor(&nb, (const void*)mega_kern, NT, 0);

    if (coop && nb >= 2) {
        void* args[] = { (void*)&mp, (void*)&aw, (void*)&esw, (void*)&out, (void*)&wsf };
        hipLaunchCooperativeKernel((void*)mega_kern, dim3(NB), dim3(NT), args, 0, stream);
    } else {
        fb_A_kern<<<NB, NT, 0, stream>>>(mp, aw, wsf);
        fb_B_kern<<<NB, NT, 0, stream>>>(esw, out, wsf);
    }
}